// Round 8
// baseline (449.251 us; speedup 1.0000x reference)
//
#include <hip/hip_runtime.h>
#include <hip/hip_bf16.h>

#define N_NODES 8192
#define EMB 256
#define NHID 64
#define LOG2E 1.44269504088896340736f
#define S_SPLIT 32
#define COLS 256       // cols per k2 block = N_NODES / S_SPLIT
#define NKT 8          // K-tiles per block = COLS / 32
#define HROW 264       // padded LDS row stride (shorts) for hT tile
#define MROW 40        // padded LDS row stride (bytes) for mask tile (8B-aligned)
#define PACK_BLOCKS 2048
#define K1_BLOCKS 2048  // N_NODES / 4

typedef __attribute__((ext_vector_type(8))) short bf16x8;
typedef __attribute__((ext_vector_type(4))) float f32x4;

static __device__ __forceinline__ short f2bf(float f) {
  __hip_bfloat16 h = __float2bfloat16(f);  // round-to-nearest-even
  return *reinterpret_cast<short*>(&h);
}

// fast bf16 round (half-up in magnitude) — used on nonnegative attention
// weights where ties-away vs ties-even rounding is noise.
static __device__ __forceinline__ short f2bf_fast(float f) {
  unsigned u = __builtin_bit_cast(unsigned, f);
  return (short)((u + 0x8000u) >> 16);
}

// Fused kernel 0+1.
//  blocks [0, PACK_BLOCKS): adj -> bitmask via ballot. 1 int/lane coalesced
//    (256 B per wave-instr, fill-shaped); 1 u64 store per 64 cols.
//  blocks [PACK_BLOCKS, +K1_BLOCKS): h = input @ W (one wave per row),
//    writes hT[d][row] bf16 + log2e-scaled s_src/s_dst.
__global__ __launch_bounds__(256) void gat_k01(
    const int* __restrict__ adj, unsigned long long* __restrict__ mask64,
    const float* __restrict__ in, const float* __restrict__ W,
    const float* __restrict__ a, short* __restrict__ hT,
    float* __restrict__ ssrc, float* __restrict__ sdst) {
  int wv = threadIdx.x >> 6, lane = threadIdx.x & 63;
  if (blockIdx.x < PACK_BLOCKS) {
    const int NW = PACK_BLOCKS * 4;               // total pack waves
    const int NG = (N_NODES * N_NODES) / 64;      // 64-col groups
    int wid = blockIdx.x * 4 + wv;
    for (int g = wid; g < NG; g += NW) {
      int v = adj[(size_t)g * 64 + lane];
      unsigned long long bal = __ballot(v != 0);  // bit l = col 64g + l
      if (lane == 0) mask64[g] = bal;
    }
    return;
  }
  int row = (blockIdx.x - PACK_BLOCKS) * 4 + wv;
  int d = lane;
  const float4* in4 = reinterpret_cast<const float4*>(in + (size_t)row * EMB);
  float acc = 0.f;
#pragma unroll 4
  for (int k4 = 0; k4 < EMB / 4; ++k4) {
    float4 x = in4[k4];
    int k = k4 * 4;
    acc = fmaf(x.x, W[(k + 0) * NHID + d], acc);
    acc = fmaf(x.y, W[(k + 1) * NHID + d], acc);
    acc = fmaf(x.z, W[(k + 2) * NHID + d], acc);
    acc = fmaf(x.w, W[(k + 3) * NHID + d], acc);
  }
  hT[(size_t)d * N_NODES + row] = f2bf(acc);
  float p1 = acc * a[d];
  float p2 = acc * a[NHID + d];
#pragma unroll
  for (int off = 32; off > 0; off >>= 1) {
    p1 += __shfl_xor(p1, off);
    p2 += __shfl_xor(p2, off);
  }
  if (lane == 0) {
    ssrc[row] = p1 * LOG2E;
    sdst[row] = p2 * LOG2E;
  }
}

// Kernel 2: fused masked-exp + P@h via bf16 MFMA.
// Block = 64 rows x 256 cols. ALL data staged to LDS up front:
//   - hT slice (33 KB, padded), sdst slice (1 KB)
//   - mask tile (2 KB from the 8 MB L2/L3-resident bitmask — replaces the
//     64 KB HBM adj read that serialized every block's staging chain).
// The K-loop touches no global memory.
__global__ __launch_bounds__(256, 4) void gat_k2(
    const unsigned char* __restrict__ maskb, const short* __restrict__ hT,
    const float* __restrict__ ssrc, const float* __restrict__ sdst,
    float* __restrict__ pacc, float* __restrict__ pz) {
  __shared__ short hlds[64 * HROW];                                  // 33792 B
  __shared__ unsigned char mlds[64 * MROW] __attribute__((aligned(8)));  // 2560 B
  __shared__ float tlds[COLS];                                       // 1024 B

  int split = blockIdx.x >> 7;
  int rb = blockIdx.x & 127;
  int tid = threadIdx.x;
  int c0 = split * COLS;
  int wv = tid >> 6, lane = tid & 63;

  // ---- stage hT slice: 64 dims x 512 B ----
#pragma unroll
  for (int p = 0; p < 8; ++p) {
    int flat = p * 4096 + tid * 16;    // byte offset within [64][512B]
    int srow = flat >> 9;              // dim
    int scol = (flat & 511) >> 1;      // short index within row
    bf16x8 v = *reinterpret_cast<const bf16x8*>(
        hT + (size_t)srow * N_NODES + c0 + scol);
    *reinterpret_cast<bf16x8*>(&hlds[srow * HROW + scol]) = v;
  }
  if (tid < 64) {
    float4 t4 = *reinterpret_cast<const float4*>(sdst + c0 + tid * 4);
    *reinterpret_cast<float4*>(&tlds[tid * 4]) = t4;
  }
  // ---- stage mask tile: 64 rows x 32 B (8 B per thread) ----
  {
    int r = tid >> 2, k = tid & 3;
    unsigned long long m = *reinterpret_cast<const unsigned long long*>(
        maskb + (size_t)(rb * 64 + r) * (N_NODES / 8) + split * 32 + k * 8);
    *reinterpret_cast<unsigned long long*>(&mlds[r * MROW + k * 8]) = m;
  }
  __syncthreads();

  int lrow = lane & 15, kg = lane >> 4;
  int r0 = rb * 64 + wv * 16;
  float s_i = ssrc[r0 + lrow];

  f32x4 acc0 = {0.f, 0.f, 0.f, 0.f};
  f32x4 acc1 = acc0, acc2 = acc0, acc3 = acc0;
  float zacc = 0.f;

#pragma unroll
  for (int kt = 0; kt < NKT; ++kt) {
    int cb = kt * 32 + kg * 8;
    // block-local mask row; banks = 10*lrow%32 distinct, kg broadcasts in-dword
    unsigned mb = mlds[(wv * 16 + lrow) * MROW + kt * 4 + kg];
    float4 tA = *reinterpret_cast<const float4*>(&tlds[cb]);
    float4 tB = *reinterpret_cast<const float4*>(&tlds[cb + 4]);
    bf16x8 b0 = *reinterpret_cast<const bf16x8*>(&hlds[(lrow + 0) * HROW + cb]);
    bf16x8 b1 = *reinterpret_cast<const bf16x8*>(&hlds[(lrow + 16) * HROW + cb]);
    bf16x8 b2 = *reinterpret_cast<const bf16x8*>(&hlds[(lrow + 32) * HROW + cb]);
    bf16x8 b3 = *reinterpret_cast<const bf16x8*>(&hlds[(lrow + 48) * HROW + cb]);

    float tv[8] = {tA.x, tA.y, tA.z, tA.w, tB.x, tB.y, tB.z, tB.w};
    bf16x8 af;
#pragma unroll
    for (int e = 0; e < 8; ++e) {
      float x = s_i + tv[e];                   // log2-domain score
      float lk = fmaxf(x, 0.2f * x);           // leakyrelu (alpha<1)
      float ev = __builtin_amdgcn_exp2f(lk);   // exp(leaky(s+t))
      float w = (mb & (1u << e)) ? ev : 0.f;   // mask
      zacc += w;
      af[e] = f2bf_fast(w);
    }
    acc0 = __builtin_amdgcn_mfma_f32_16x16x32_bf16(af, b0, acc0, 0, 0, 0);
    acc1 = __builtin_amdgcn_mfma_f32_16x16x32_bf16(af, b1, acc1, 0, 0, 0);
    acc2 = __builtin_amdgcn_mfma_f32_16x16x32_bf16(af, b2, acc2, 0, 0, 0);
    acc3 = __builtin_amdgcn_mfma_f32_16x16x32_bf16(af, b3, acc3, 0, 0, 0);
  }

  // Z: A-layout row = lane&15; sum over lanes {r, r+16, r+32, r+48}
  float z = zacc;
  z += __shfl_xor(z, 16);
  z += __shfl_xor(z, 32);
  if (lane < 16) pz[(size_t)split * N_NODES + r0 + lane] = z;

  // C/D layout: row = (lane>>4)*4 + reg, col = lane&15
  float* pa = pacc + (size_t)split * (N_NODES * NHID);
#pragma unroll
  for (int reg = 0; reg < 4; ++reg) {
    int orow = r0 + kg * 4 + reg;
    pa[(size_t)orow * NHID + 0 * 16 + lrow] = acc0[reg];
    pa[(size_t)orow * NHID + 1 * 16 + lrow] = acc1[reg];
    pa[(size_t)orow * NHID + 2 * 16 + lrow] = acc2[reg];
    pa[(size_t)orow * NHID + 3 * 16 + lrow] = acc3[reg];
  }
}

// Kernel 3: combine split partials and normalize (float4 per thread).
__global__ __launch_bounds__(256) void gat_k3(
    const float* __restrict__ pacc, const float* __restrict__ pz,
    float* __restrict__ out) {
  int t = blockIdx.x * 256 + threadIdx.x;  // indexes float4
  int row = t >> 4;                        // 16 float4 per row (NHID=64)
  float4 num = {0.f, 0.f, 0.f, 0.f};
  float den = 0.f;
#pragma unroll 8
  for (int s = 0; s < S_SPLIT; ++s) {
    float4 p = *reinterpret_cast<const float4*>(
        &pacc[(size_t)s * (N_NODES * NHID) + (size_t)t * 4]);
    num.x += p.x; num.y += p.y; num.z += p.z; num.w += p.w;
    den += pz[(size_t)s * N_NODES + row];
  }
  float r = 1.f / den;
  float4 o = {num.x * r, num.y * r, num.z * r, num.w * r};
  *reinterpret_cast<float4*>(&out[(size_t)t * 4]) = o;
}

extern "C" void kernel_launch(void* const* d_in, const int* in_sizes, int n_in,
                              void* d_out, int out_size, void* d_ws, size_t ws_size,
                              hipStream_t stream) {
  (void)in_sizes; (void)n_in; (void)out_size; (void)ws_size;
  const float* in = (const float*)d_in[0];
  const int* adj = (const int*)d_in[1];
  const float* W = (const float*)d_in[2];
  const float* a = (const float*)d_in[3];
  float* out = (float*)d_out;

  // ws: hT (1 MB) | ssrc (32K) | sdst (32K) | pz (1 MB) | pacc (64 MB) | mask (8 MB)
  char* w = (char*)d_ws;
  short* hT = (short*)w;
  float* ssrc = (float*)(w + (1u << 20));
  float* sdst = ssrc + N_NODES;
  float* pz = sdst + N_NODES;
  float* pacc = pz + (size_t)S_SPLIT * N_NODES;
  unsigned long long* mask64 =
      (unsigned long long*)(pacc + (size_t)S_SPLIT * (N_NODES * NHID));

  gat_k01<<<PACK_BLOCKS + K1_BLOCKS, 256, 0, stream>>>(adj, mask64, in, W, a,
                                                       hT, ssrc, sdst);
  gat_k2<<<128 * S_SPLIT, 256, 0, stream>>>((const unsigned char*)mask64, hT,
                                            ssrc, sdst, pacc, pz);
  gat_k3<<<(N_NODES * NHID) / (256 * 4), 256, 0, stream>>>(pacc, pz, out);
}

// Round 9
// 425.482 us; speedup vs baseline: 1.0559x; 1.0559x over previous
//
#include <hip/hip_runtime.h>
#include <hip/hip_bf16.h>

#define N_NODES 8192
#define EMB 256
#define NHID 64
#define LOG2E 1.44269504088896340736f
#define S_SPLIT 32
#define COLS 256       // cols per k2 block = N_NODES / S_SPLIT
#define NKT 8          // K-tiles per tile = COLS / 32
#define NT 4           // row-tiles per persistent block
#define HROW 264       // padded LDS row stride (shorts) for hT tile
#define MROW 36        // padded LDS row stride (bytes) for mask tile

typedef __attribute__((ext_vector_type(8))) short bf16x8;
typedef __attribute__((ext_vector_type(4))) float f32x4;

static __device__ __forceinline__ short f2bf(float f) {
  __hip_bfloat16 h = __float2bfloat16(f);  // round-to-nearest-even
  return *reinterpret_cast<short*>(&h);
}

// fast bf16 round (half-up in magnitude) — used on nonnegative attention
// weights where ties-away vs ties-even rounding is noise.
static __device__ __forceinline__ short f2bf_fast(float f) {
  unsigned u = __builtin_bit_cast(unsigned, f);
  return (short)((u + 0x8000u) >> 16);
}

// Kernel 1: h = input @ W. One wave per row (lane = d).
// Writes hT[d][row] (bf16, transposed) + log2e-scaled s_src/s_dst.
__global__ __launch_bounds__(256) void gat_k1(
    const float* __restrict__ in, const float* __restrict__ W,
    const float* __restrict__ a, short* __restrict__ hT,
    float* __restrict__ ssrc, float* __restrict__ sdst) {
  int wave = threadIdx.x >> 6, lane = threadIdx.x & 63;
  int row = blockIdx.x * 4 + wave;
  int d = lane;
  const float4* in4 = reinterpret_cast<const float4*>(in + (size_t)row * EMB);
  float acc = 0.f;
#pragma unroll 4
  for (int k4 = 0; k4 < EMB / 4; ++k4) {
    float4 x = in4[k4];
    int k = k4 * 4;
    acc = fmaf(x.x, W[(k + 0) * NHID + d], acc);
    acc = fmaf(x.y, W[(k + 1) * NHID + d], acc);
    acc = fmaf(x.z, W[(k + 2) * NHID + d], acc);
    acc = fmaf(x.w, W[(k + 3) * NHID + d], acc);
  }
  hT[(size_t)d * N_NODES + row] = f2bf(acc);
  float p1 = acc * a[d];
  float p2 = acc * a[NHID + d];
#pragma unroll
  for (int off = 32; off > 0; off >>= 1) {
    p1 += __shfl_xor(p1, off);
    p2 += __shfl_xor(p2, off);
  }
  if (lane == 0) {
    ssrc[row] = p1 * LOG2E;
    sdst[row] = p2 * LOG2E;
  }
}

// issue the 64 KB adj tile for row-block rb into registers (16 int4/thread);
// each 32-lane half-wave reads one contiguous 1 KB row slice.
static __device__ __forceinline__ void adj_issue(
    const int* __restrict__ adj, int rb, int c0, int wv, int lane,
    int4 (&pre)[16]) {
  int h = lane >> 5, sl = lane & 31;
#pragma unroll
  for (int p = 0; p < 8; ++p) {
    int r = wv * 16 + p * 2 + h;
    const int* ap = adj + (size_t)(rb * 64 + r) * N_NODES + c0 + sl * 8;
    pre[p * 2 + 0] = *reinterpret_cast<const int4*>(ap);
    pre[p * 2 + 1] = *reinterpret_cast<const int4*>(ap + 4);
  }
}

// pack the prefetched adj ints into the LDS bitmask buffer.
static __device__ __forceinline__ void adj_pack(
    const int4 (&pre)[16], unsigned char* __restrict__ mbuf, int wv, int lane) {
  int h = lane >> 5, sl = lane & 31;
#pragma unroll
  for (int p = 0; p < 8; ++p) {
    int r = wv * 16 + p * 2 + h;
    int4 v0 = pre[p * 2 + 0], v1 = pre[p * 2 + 1];
    unsigned b = (unsigned)(v0.x != 0) | ((unsigned)(v0.y != 0) << 1) |
                 ((unsigned)(v0.z != 0) << 2) | ((unsigned)(v0.w != 0) << 3) |
                 ((unsigned)(v1.x != 0) << 4) | ((unsigned)(v1.y != 0) << 5) |
                 ((unsigned)(v1.z != 0) << 6) | ((unsigned)(v1.w != 0) << 7);
    mbuf[r * MROW + sl] = (unsigned char)b;
  }
}

// Kernel 2: persistent-block fused masked-exp + P@h via bf16 MFMA.
// 1024 blocks (4/CU, all resident). Block fixes split (hT/sdst staged ONCE),
// iterates NT=4 row-tiles. Next tile's adj prefetches into registers while
// the current tile's all-LDS K-loop runs (T14 async-stage split) — adj HBM
// latency hides under compute; adj is read exactly once, by its consumer.
__global__ __launch_bounds__(256, 4) void gat_k2(
    const int* __restrict__ adj, const short* __restrict__ hT,
    const float* __restrict__ ssrc, const float* __restrict__ sdst,
    float* __restrict__ pacc, float* __restrict__ pz) {
  __shared__ short hlds[64 * HROW];              // 33792 B
  __shared__ unsigned char mlds[2][64 * MROW];   // 2x2304 B
  __shared__ float tlds[COLS];                   // 1024 B

  int split = blockIdx.x & 31;
  int slot = blockIdx.x >> 5;  // 0..31 -> rb = slot*NT + t
  int tid = threadIdx.x;
  int c0 = split * COLS;
  int wv = tid >> 6, lane = tid & 63;
  int lrow = lane & 15, kg = lane >> 4;

  int4 pre[16];
  // prologue: adj tile 0 (longest latency — issue first), then hT/sdst stage
  adj_issue(adj, slot * NT, c0, wv, lane, pre);
#pragma unroll
  for (int p = 0; p < 8; ++p) {
    int flat = p * 4096 + tid * 16;    // byte offset within [64][512B]
    int srow = flat >> 9;              // dim
    int scol = (flat & 511) >> 1;      // short index within row
    bf16x8 v = *reinterpret_cast<const bf16x8*>(
        hT + (size_t)srow * N_NODES + c0 + scol);
    *reinterpret_cast<bf16x8*>(&hlds[srow * HROW + scol]) = v;
  }
  if (tid < 64) {
    float4 t4 = *reinterpret_cast<const float4*>(sdst + c0 + tid * 4);
    *reinterpret_cast<float4*>(&tlds[tid * 4]) = t4;
  }
  adj_pack(pre, mlds[0], wv, lane);
  __syncthreads();

  float* pa = pacc + (size_t)split * (N_NODES * NHID);

#pragma unroll
  for (int t = 0; t < NT; ++t) {
    int rb = slot * NT + t;
    int cur = t & 1;
    // issue next tile's adj loads; they ride out the K-loop (no global ops
    // inside it, so no vmcnt wait touches them until adj_pack below)
    if (t + 1 < NT) adj_issue(adj, rb + 1, c0, wv, lane, pre);

    int r0 = rb * 64 + wv * 16;
    float s_i = ssrc[r0 + lrow];
    f32x4 acc0 = {0.f, 0.f, 0.f, 0.f};
    f32x4 acc1 = acc0, acc2 = acc0, acc3 = acc0;
    float zacc = 0.f;

#pragma unroll
    for (int kt = 0; kt < NKT; ++kt) {
      int cb = kt * 32 + kg * 8;
      unsigned mb = mlds[cur][(wv * 16 + lrow) * MROW + kt * 4 + kg];
      float4 tA = *reinterpret_cast<const float4*>(&tlds[cb]);
      float4 tB = *reinterpret_cast<const float4*>(&tlds[cb + 4]);
      bf16x8 b0 = *reinterpret_cast<const bf16x8*>(&hlds[(lrow + 0) * HROW + cb]);
      bf16x8 b1 = *reinterpret_cast<const bf16x8*>(&hlds[(lrow + 16) * HROW + cb]);
      bf16x8 b2 = *reinterpret_cast<const bf16x8*>(&hlds[(lrow + 32) * HROW + cb]);
      bf16x8 b3 = *reinterpret_cast<const bf16x8*>(&hlds[(lrow + 48) * HROW + cb]);

      float tv[8] = {tA.x, tA.y, tA.z, tA.w, tB.x, tB.y, tB.z, tB.w};
      bf16x8 af;
#pragma unroll
      for (int e = 0; e < 8; ++e) {
        float x = s_i + tv[e];                   // log2-domain score
        float lk = fmaxf(x, 0.2f * x);           // leakyrelu (alpha<1)
        float ev = __builtin_amdgcn_exp2f(lk);   // exp(leaky(s+t))
        float w = (mb & (1u << e)) ? ev : 0.f;   // mask
        zacc += w;
        af[e] = f2bf_fast(w);
      }
      acc0 = __builtin_amdgcn_mfma_f32_16x16x32_bf16(af, b0, acc0, 0, 0, 0);
      acc1 = __builtin_amdgcn_mfma_f32_16x16x32_bf16(af, b1, acc1, 0, 0, 0);
      acc2 = __builtin_amdgcn_mfma_f32_16x16x32_bf16(af, b2, acc2, 0, 0, 0);
      acc3 = __builtin_amdgcn_mfma_f32_16x16x32_bf16(af, b3, acc3, 0, 0, 0);
    }

    // writeout tile t (stores don't block the in-flight adj loads)
    float z = zacc;
    z += __shfl_xor(z, 16);
    z += __shfl_xor(z, 32);
    if (lane < 16) pz[(size_t)split * N_NODES + r0 + lane] = z;
#pragma unroll
    for (int reg = 0; reg < 4; ++reg) {
      int orow = r0 + kg * 4 + reg;
      pa[(size_t)orow * NHID + 0 * 16 + lrow] = acc0[reg];
      pa[(size_t)orow * NHID + 1 * 16 + lrow] = acc1[reg];
      pa[(size_t)orow * NHID + 2 * 16 + lrow] = acc2[reg];
      pa[(size_t)orow * NHID + 3 * 16 + lrow] = acc3[reg];
    }

    // pack next tile's mask (first point that waits on the prefetch loads)
    if (t + 1 < NT) adj_pack(pre, mlds[cur ^ 1], wv, lane);
    __syncthreads();
  }
}

// Kernel 3: combine split partials and normalize (float4 per thread).
__global__ __launch_bounds__(256) void gat_k3(
    const float* __restrict__ pacc, const float* __restrict__ pz,
    float* __restrict__ out) {
  int t = blockIdx.x * 256 + threadIdx.x;  // indexes float4
  int row = t >> 4;                        // 16 float4 per row (NHID=64)
  float4 num = {0.f, 0.f, 0.f, 0.f};
  float den = 0.f;
#pragma unroll 8
  for (int s = 0; s < S_SPLIT; ++s) {
    float4 p = *reinterpret_cast<const float4*>(
        &pacc[(size_t)s * (N_NODES * NHID) + (size_t)t * 4]);
    num.x += p.x; num.y += p.y; num.z += p.z; num.w += p.w;
    den += pz[(size_t)s * N_NODES + row];
  }
  float r = 1.f / den;
  float4 o = {num.x * r, num.y * r, num.z * r, num.w * r};
  *reinterpret_cast<float4*>(&out[(size_t)t * 4]) = o;
}

extern "C" void kernel_launch(void* const* d_in, const int* in_sizes, int n_in,
                              void* d_out, int out_size, void* d_ws, size_t ws_size,
                              hipStream_t stream) {
  (void)in_sizes; (void)n_in; (void)out_size; (void)ws_size;
  const float* in = (const float*)d_in[0];
  const int* adj = (const int*)d_in[1];
  const float* W = (const float*)d_in[2];
  const float* a = (const float*)d_in[3];
  float* out = (float*)d_out;

  // ws: hT (1 MB) | ssrc (32K) | sdst (32K) | pz (1 MB) | pacc (64 MB)
  char* w = (char*)d_ws;
  short* hT = (short*)w;
  float* ssrc = (float*)(w + (1u << 20));
  float* sdst = ssrc + N_NODES;
  float* pz = sdst + N_NODES;
  float* pacc = pz + (size_t)S_SPLIT * N_NODES;

  gat_k1<<<N_NODES / 4, 256, 0, stream>>>(in, W, a, hT, ssrc, sdst);
  gat_k2<<<(128 / NT) * S_SPLIT, 256, 0, stream>>>(adj, hT, ssrc, sdst, pacc,
                                                   pz);
  gat_k3<<<(N_NODES * NHID) / (256 * 4), 256, 0, stream>>>(pacc, pz, out);
}